// Round 6
// baseline (652.648 us; speedup 1.0000x reference)
//
#include <hip/hip_runtime.h>
#include <hip/hip_bf16.h>
#include <math.h>

#define NH 8
#define DKk 256
#define DVv 512
#define Bn 2
#define Tn 2048
#define HID 2048
#define EPSf 1e-5f

typedef __bf16 bf16x8 __attribute__((ext_vector_type(8)));
typedef float f32x4 __attribute__((ext_vector_type(4)));
typedef unsigned short us8 __attribute__((ext_vector_type(8)));
typedef unsigned int u32x4 __attribute__((ext_vector_type(4)));
using bf16 = __hip_bfloat16;
typedef unsigned short ushort_t;

__device__ __forceinline__ void gload_lds16(const void* g, void* lds_base) {
  __builtin_amdgcn_global_load_lds(
      (const __attribute__((address_space(1))) void*)g,
      (__attribute__((address_space(3))) void*)lds_base, 16, 0, 0);
}

__device__ __forceinline__ ushort_t f2bf_raw(float f) {
  bf16 h = __float2bfloat16(f);
  return *reinterpret_cast<ushort_t*>(&h);
}
__device__ __forceinline__ float bf2f_raw(ushort_t u) {
  union { unsigned int i; float f; } v; v.i = ((unsigned int)u) << 16; return v.f;
}

// ---------------- fp32 -> bf16 elementwise (vectorized x4) ----------------
__global__ void k_f32_to_bf16(const float4* __restrict__ in, ushort4* __restrict__ out, int n4) {
  int i = blockIdx.x * blockDim.x + threadIdx.x;
  if (i >= n4) return;
  float4 v = in[i];
  ushort4 o;
  o.x = f2bf_raw(v.x); o.y = f2bf_raw(v.y); o.z = f2bf_raw(v.z); o.w = f2bf_raw(v.w);
  out[i] = o;
}

// ---------------- W (K,N) fp32 -> WT (N,K) bf16 ----------------
__global__ void k_transpose_w(const float* __restrict__ W, bf16* __restrict__ WT, int K, int N) {
  __shared__ float t[32][33];
  int n0 = blockIdx.x * 32, k0 = blockIdx.y * 32;
  int tx = threadIdx.x, ty = threadIdx.y;
#pragma unroll
  for (int i = 0; i < 4; i++)
    t[ty + i * 8][tx] = W[(size_t)(k0 + ty + i * 8) * N + n0 + tx];
  __syncthreads();
#pragma unroll
  for (int i = 0; i < 4; i++)
    WT[(size_t)(n0 + ty + i * 8) * K + k0 + tx] = __float2bfloat16(t[tx][ty + i * 8]);
}

// ---------------- v (b,t,h,dv) bf16 -> vS[bh][kt][chunk(4)][dv(512)] 16B units ----------------
__global__ void k_build_vS(const ushort_t* __restrict__ v, ushort_t* __restrict__ vS) {
  __shared__ ushort_t t[32 * 520];
  const int tid = threadIdx.x;
  const int kt = blockIdx.x;
  const int bh = blockIdx.y;
  const int b = bh >> 3, h = bh & 7;
#pragma unroll
  for (int r = 0; r < 8; r++) {
    int j = r * 4 + (tid >> 6);
    int vec = tid & 63;
    us8 d = *(const us8*)(v + (((size_t)(b * Tn + kt * 32 + j) * NH + h) * DVv) + vec * 8);
    *(us8*)(&t[j * 520 + vec * 8]) = d;
  }
  __syncthreads();
#pragma unroll
  for (int u = 0; u < 8; u++) {
    int uid = u * 256 + tid;
    int chunk = uid >> 9;
    int dv = uid & 511;
    us8 o;
#pragma unroll
    for (int jj = 0; jj < 8; jj++) o[jj] = t[(chunk * 8 + jj) * 520 + dv];
    *(us8*)(vS + ((size_t)(bh * 64 + kt) * 2048 + chunk * 512 + dv) * 8) = o;
  }
}

// ---------------- RoPE in-place on bf16 (b,t,h,dk), scale folded ----------------
__global__ void k_rope(bf16* __restrict__ x, float scale) {
  int tid = blockIdx.x * 256 + threadIdx.x;
  int i = tid & 127;
  int h = (tid >> 7) & 7;
  int t = (tid >> 10) & (Tn - 1);
  int b = tid >> 21;
  float inv = exp2f(-(float)i * (13.287712379549449f / 128.0f));
  float ang = (float)t * inv;
  float s, c;
  sincosf(ang, &s, &c);
  size_t base = ((size_t)(b * Tn + t) * NH + h) * DKk + i;
  float x1 = __bfloat162float(x[base]);
  float x2 = __bfloat162float(x[base + 128]);
  x[base]       = __float2bfloat16((x1 * c - x2 * s) * scale);
  x[base + 128] = __float2bfloat16((x2 * c + x1 * s) * scale);
}

// ---------------- m97-style GEMM (out-proj) ----------------
template <bool OUT_BF16>
__global__ __launch_bounds__(256) void k_gemm(const bf16* __restrict__ A, const bf16* __restrict__ BT,
                                              void* __restrict__ Cout, int M, int N, int K) {
  __shared__ __align__(16) bf16 a_lds[128 * 32];
  __shared__ __align__(16) bf16 b_lds[128 * 32];
  const int tid = threadIdx.x;
  const int l = tid & 63;
  const int w = tid >> 6;
  const int wr = w >> 1, wc = w & 1;
  const int m0 = blockIdx.y * 128, n0 = blockIdx.x * 128;
  const int quad = l >> 4, c16 = l & 15;

  const int lrow = l >> 2;
  const int loff = (l & 3) * 16;
  const char* aG0 = (const char*)(A + (size_t)(m0 + w * 32 + lrow) * K) + loff;
  const char* aG1 = (const char*)(A + (size_t)(m0 + w * 32 + 16 + lrow) * K) + loff;
  const char* bG0 = (const char*)(BT + (size_t)(n0 + w * 32 + lrow) * K) + loff;
  const char* bG1 = (const char*)(BT + (size_t)(n0 + w * 32 + 16 + lrow) * K) + loff;
  char* aL0 = (char*)a_lds + w * 2048;
  char* aL1 = (char*)a_lds + w * 2048 + 1024;
  char* bL0 = (char*)b_lds + w * 2048;
  char* bL1 = (char*)b_lds + w * 2048 + 1024;

  f32x4 acc[4][4];
  const f32x4 fz = {0.f, 0.f, 0.f, 0.f};
#pragma unroll
  for (int r = 0; r < 4; r++)
#pragma unroll
    for (int c = 0; c < 4; c++) acc[r][c] = fz;

  for (int k0 = 0; k0 < K; k0 += 32) {
    __syncthreads();
    size_t kb = (size_t)k0 * 2;
    gload_lds16(aG0 + kb, aL0);
    gload_lds16(aG1 + kb, aL1);
    gload_lds16(bG0 + kb, bL0);
    gload_lds16(bG1 + kb, bL1);
    __syncthreads();
    bf16x8 af[4], bfv[4];
#pragma unroll
    for (int r = 0; r < 4; r++)
      af[r] = *(const bf16x8*)(a_lds + (wr * 64 + r * 16 + c16) * 32 + quad * 8);
#pragma unroll
    for (int c = 0; c < 4; c++)
      bfv[c] = *(const bf16x8*)(b_lds + (wc * 64 + c * 16 + c16) * 32 + quad * 8);
#pragma unroll
    for (int r = 0; r < 4; r++)
#pragma unroll
      for (int c = 0; c < 4; c++)
        acc[r][c] = __builtin_amdgcn_mfma_f32_16x16x32_bf16(af[r], bfv[c], acc[r][c], 0, 0, 0);
  }

#pragma unroll
  for (int r = 0; r < 4; r++)
#pragma unroll
    for (int c = 0; c < 4; c++)
#pragma unroll
      for (int rr = 0; rr < 4; rr++) {
        int m = m0 + wr * 64 + r * 16 + quad * 4 + rr;
        int n = n0 + wc * 64 + c * 16 + c16;
        float val = acc[r][c][rr];
        if (OUT_BF16) ((bf16*)Cout)[(size_t)m * N + n] = __float2bfloat16(val);
        else          ((float*)Cout)[(size_t)m * N + n] = val;
      }
}

// ================= 256x256 8-phase GEMM, v4: counted-lgkm read-ahead =================
// ph1 issues R1{A0-3,B01}(12) then [sched_barrier] R2{A4-7}(8); waits lgkmcnt(8) -> R1
// landed, R2 flies under Q00. ph2 issues R3{B23}(4); waits lgkmcnt(4) -> R2 landed.
// ph3 waits lgkmcnt(0) -> R3 landed. ph4 no reads. DS completion is in-order -> counted
// waits drain exactly the oldest groups. Region ledger: buf.A all-wave-drained by ph2's
// lgkm(4)+closing barrier -> ph3/4 A-stage safe; R3 drained at ph3 lgkm(0) -> ph5 B-stage
// safe. Stages + vmcnt(4) ledger unchanged from v3 (verified R5).
#define BARX() asm volatile("s_barrier" ::: "memory")
#define LGKM0() { asm volatile("s_waitcnt lgkmcnt(0)" ::: "memory"); __builtin_amdgcn_sched_barrier(0); }
#define LGKM8() { asm volatile("s_waitcnt lgkmcnt(8)" ::: "memory"); __builtin_amdgcn_sched_barrier(0); }
#define LGKM4() { asm volatile("s_waitcnt lgkmcnt(4)" ::: "memory"); __builtin_amdgcn_sched_barrier(0); }
#define VMW4() asm volatile("s_waitcnt vmcnt(4)" ::: "memory")
#define VMW0() asm volatile("s_waitcnt vmcnt(0)" ::: "memory")
#define PRIO1 __builtin_amdgcn_s_setprio(1)
#define PRIO0 __builtin_amdgcn_s_setprio(0)
#define SCHEDB() __builtin_amdgcn_sched_barrier(0)

#define QUADQ(MB, NB)                                                              \
  { _Pragma("unroll") for (int kk_ = 0; kk_ < 2; ++kk_)                            \
    _Pragma("unroll") for (int mf_ = 0; mf_ < 4; ++mf_)                            \
    _Pragma("unroll") for (int nf_ = 0; nf_ < 2; ++nf_)                            \
      acc[(MB) + mf_][(NB) + nf_] = __builtin_amdgcn_mfma_f32_16x16x32_bf16(       \
          ar[(MB) + mf_][kk_], br[(NB) + nf_][kk_],                                \
          acc[(MB) + mf_][(NB) + nf_], 0, 0, 0); }

__global__ __launch_bounds__(512, 2) void k_gemm8(const bf16* __restrict__ A, const bf16* __restrict__ BT,
                                                  bf16* __restrict__ O0, bf16* __restrict__ O1,
                                                  int nsplit, int M, int Ntot, int K) {
  extern __shared__ char lds[];
  const int tid = threadIdx.x;
  const int lane = tid & 63;
  const int w = tid >> 6;        // 0..7
  const int wr = w >> 2;         // 0..1 (M half)
  const int wc = w & 3;          // 0..3 (N quarter)
  const int quad = lane >> 4, c16 = lane & 15;
  const int m0 = blockIdx.y * 256, n0 = blockIdx.x * 256;

  const int srow = (w << 4) | (lane >> 3);
  const int gsw = (((lane & 7) ^ (lane >> 3)) << 4);   // inverse-swizzled source granule
  const size_t rowBytes = (size_t)K * 2;
  const char* aS = (const char*)(A + (size_t)(m0 + srow) * K) + gsw;
  const char* bS = (const char*)(BT + (size_t)(n0 + srow) * K) + gsw;

  auto stage = [&](int matB, int buf, int h, int t) {
    const char* base = (matB ? bS : aS) + (size_t)h * 128 * rowBytes + (size_t)t * 128;
    char* ldst = lds + buf * 65536 + matB * 32768 + h * 16384 + w * 2048;
    gload_lds16(base, ldst);
    gload_lds16(base + 8 * rowBytes, ldst + 1024);
  };
  auto ldA = [&](int buf, int mf, int kk) -> bf16x8 {
    int row = wr * 128 + mf * 16 + c16;
    return *(const bf16x8*)(lds + buf * 65536 + row * 128 + ((((kk << 2) | quad) ^ (c16 & 7)) << 4));
  };
  auto ldB = [&](int buf, int nf, int kk) -> bf16x8 {
    int row = wc * 64 + nf * 16 + c16;
    return *(const bf16x8*)(lds + buf * 65536 + 32768 + row * 128 + ((((kk << 2) | quad) ^ (c16 & 7)) << 4));
  };

  f32x4 acc[8][4];
  const f32x4 fz = {0.f, 0.f, 0.f, 0.f};
#pragma unroll
  for (int i = 0; i < 8; i++)
#pragma unroll
    for (int j = 0; j < 4; j++) acc[i][j] = fz;
  bf16x8 ar[8][2], br[4][2];

  const int nT = K >> 6;
  const int nIter = nT >> 1;

  // prologue: tile0 full + tile1 A -> 12 loads; vmcnt(4) leaves t1.A in flight
  stage(0, 0, 0, 0); stage(0, 0, 1, 0);
  stage(1, 0, 0, 0); stage(1, 0, 1, 0);
  stage(0, 1, 0, 1); stage(0, 1, 1, 1);
  VMW4();
  BARX();

  for (int it = 0; it < nIter; ++it) {
    const int t = it * 2;
    const bool last = (it == nIter - 1);
    // ---- ph1: issue R1{A0-3,B01} + R2{A4-7} (buf0); stage (t+1)B0; lgkm(8); Q00 ----
#pragma unroll
    for (int mf = 0; mf < 4; ++mf) { ar[mf][0] = ldA(0, mf, 0); ar[mf][1] = ldA(0, mf, 1); }
#pragma unroll
    for (int nf = 0; nf < 2; ++nf) { br[nf][0] = ldB(0, nf, 0); br[nf][1] = ldB(0, nf, 1); }
    SCHEDB();   // pin R1 before R2 in the DS queue
#pragma unroll
    for (int mf = 4; mf < 8; ++mf) { ar[mf][0] = ldA(0, mf, 0); ar[mf][1] = ldA(0, mf, 1); }
    stage(1, 1, 0, t + 1);
    BARX(); LGKM8();
    PRIO1; QUADQ(0, 0); PRIO0;
    BARX();
    // ---- ph2: issue R3{B23}; stage (t+1)B1; lgkm(4); Q10 ----
#pragma unroll
    for (int nf = 2; nf < 4; ++nf) { br[nf][0] = ldB(0, nf, 0); br[nf][1] = ldB(0, nf, 1); }
    stage(1, 1, 1, t + 1);
    BARX(); LGKM4();
    PRIO1; QUADQ(4, 0); PRIO0;
    BARX();
    // ---- ph3: stage (t+2)A0; lgkm(0); Q01 ----
    if (!last) stage(0, 0, 0, t + 2);
    BARX(); LGKM0();
    PRIO1; QUADQ(0, 2); PRIO0;
    BARX();
    // ---- ph4: stage (t+2)A1; Q11; vmcnt(4) -> tile t+1 landed ----
    if (!last) stage(0, 0, 1, t + 2);
    BARX();
    PRIO1; QUADQ(4, 2); PRIO0;
    if (!last) { VMW4(); } else { VMW0(); }
    BARX();
    // ---- ph5: issue R1+R2 (buf1); stage (t+2)B0; lgkm(8); Q00 ----
#pragma unroll
    for (int mf = 0; mf < 4; ++mf) { ar[mf][0] = ldA(1, mf, 0); ar[mf][1] = ldA(1, mf, 1); }
#pragma unroll
    for (int nf = 0; nf < 2; ++nf) { br[nf][0] = ldB(1, nf, 0); br[nf][1] = ldB(1, nf, 1); }
    SCHEDB();
#pragma unroll
    for (int mf = 4; mf < 8; ++mf) { ar[mf][0] = ldA(1, mf, 0); ar[mf][1] = ldA(1, mf, 1); }
    if (!last) stage(1, 0, 0, t + 2);
    BARX(); LGKM8();
    PRIO1; QUADQ(0, 0); PRIO0;
    BARX();
    // ---- ph6: issue R3 (buf1); stage (t+2)B1; lgkm(4); Q10 ----
#pragma unroll
    for (int nf = 2; nf < 4; ++nf) { br[nf][0] = ldB(1, nf, 0); br[nf][1] = ldB(1, nf, 1); }
    if (!last) stage(1, 0, 1, t + 2);
    BARX(); LGKM4();
    PRIO1; QUADQ(4, 0); PRIO0;
    BARX();
    // ---- ph7: stage (t+3)A0; lgkm(0); Q01 ----
    if (!last) stage(0, 1, 0, t + 3);
    BARX(); LGKM0();
    PRIO1; QUADQ(0, 2); PRIO0;
    BARX();
    // ---- ph8: stage (t+3)A1; Q11; vmcnt(4) ----
    if (!last) stage(0, 1, 1, t + 3);
    BARX();
    PRIO1; QUADQ(4, 2); PRIO0;
    if (!last) VMW4();
    BARX();
  }

  bf16* Ob; int ldo, nc0;
  if (n0 < nsplit) { Ob = O0; ldo = nsplit; nc0 = n0; }
  else             { Ob = O1; ldo = Ntot - nsplit; nc0 = n0 - nsplit; }
#pragma unroll
  for (int mf = 0; mf < 8; ++mf)
#pragma unroll
    for (int nf = 0; nf < 4; ++nf)
#pragma unroll
      for (int rr = 0; rr < 4; ++rr) {
        int m = m0 + wr * 128 + mf * 16 + quad * 4 + rr;
        int n = nc0 + wc * 64 + nf * 16 + c16;
        Ob[(size_t)m * ldo + n] = __float2bfloat16(acc[mf][nf][rr]);
      }
}

// ---------------- Retention v5: swapped-S, in-register P, per-wave full-dv PV ----------------
// S^T = mfma(K, Q): lane c16 = wave's q-row i, (quad,r) = j. P never touches LDS: pack to
// bf16 pairs + 8 __shfl redistribute into the PV A-fragment (lane c16=i, k-octet j=quad*8+e).
// Wave w owns rows w*16..+15 x ALL 512 dv: acc[32] f32x4 (128 regs, same as before).
// Decay factored: gamma^d = gamma^base * gamma^(-off); off-table (8 consts) hoisted; 1 exp2/tile.
// RMS wave-local (no cross-wave reduce). LDS 64KB: K[2][16KB]@0, V[32KB]@32768 -> 2 blk/CU.
// 3 barriers/tile. Ledger: entry [V(t-1)8, K(t)4]; vmcnt(4)->PV; lgkm0+bar; stageV(t);
// vmcnt(8) drains K(t); bar; S(t); stageK(t+1). Heavy/light pairing (c, c+256) kept.
#define SBARR() { __builtin_amdgcn_sched_barrier(0); __builtin_amdgcn_s_barrier(); }

__global__ __launch_bounds__(256, 2) void k_retention(const bf16* __restrict__ q, const bf16* __restrict__ k,
                                                      const char* __restrict__ vS, const bf16* __restrict__ g,
                                                      const float* __restrict__ gnw, bf16* __restrict__ X) {
  extern __shared__ char smem[];
  bf16* o_lds = (bf16*)smem;   // epilogue alias (64KB)

  const int tid = threadIdx.x;
  const int l = tid & 63, w = tid >> 6;
  const int quad = l >> 4, c16 = l & 15;

  const int bid = blockIdx.x;
  const int u = (bid & 255) >> 4;
  const int qt = (bid < 256) ? (31 - u) : u;   // heavy half then light half
  const int bh = bid & 15;
  const int b = bh >> 3, h = bh & 7;
  const int q0 = qt * 64;

  bf16x8 qf[8];
  {
    const bf16* qrow = q + ((size_t)(b * Tn + q0 + w * 16 + c16) * NH + h) * DKk + quad * 8;
#pragma unroll
    for (int c = 0; c < 8; c++) qf[c] = *(const bf16x8*)(qrow + c * 32);
  }

  const float log2g = log2f(1.0f - exp2f(-5.0f - (float)h));

  // hoisted decay off-table: gamma^(-(jt*16 + quad*4 + r))
  float cinv[2][4];
#pragma unroll
  for (int jt = 0; jt < 2; jt++)
#pragma unroll
    for (int r = 0; r < 4; r++)
      cinv[jt][r] = exp2f(-log2g * (float)(jt * 16 + quad * 4 + r));

  f32x4 acc[32];
  const f32x4 fz = {0.f, 0.f, 0.f, 0.f};
#pragma unroll
  for (int n = 0; n < 32; n++) acc[n] = fz;

  const int ktmax = 2 * qt + 1;
  const float Dcut = 30.0f / (-log2g);
  int kt0 = (int)fmaxf(0.0f, floorf(((float)q0 - Dcut) * (1.0f / 32.0f)));

  const char* vS_tilebase = vS + (size_t)(bh * 64) * 32768;

  auto stageK = [&](int kt) {
    const int pb = (kt - kt0) & 1;
#pragma unroll
    for (int i = 0; i < 4; i++) {
      int instr = w * 4 + i;
      int j = instr * 2 + (l >> 5);
      int cg = (l & 31) ^ (j & 7);
      const char* gp = (const char*)(k + ((size_t)(b * Tn + kt * 32 + j) * NH + h) * DKk) + cg * 16;
      gload_lds16(gp, smem + pb * 16384 + instr * 1024);
    }
  };
  auto stageV = [&](int kt) {
#pragma unroll
    for (int i = 0; i < 8; i++) {
      int instr = w * 8 + i;
      const char* gp = vS_tilebase + (size_t)kt * 32768 + instr * 1024 + l * 16;
      gload_lds16(gp, smem + 32768 + instr * 1024);
    }
  };

  // S(kt): swapped QK^T -> decay -> pack -> shfl-redistribute -> PV A-fragment
  auto S_phase = [&](int kt) -> bf16x8 {
    const int pb = (kt - kt0) & 1;
    f32x4 sacc[2] = {fz, fz};
#pragma unroll
    for (int jt = 0; jt < 2; jt++)
#pragma unroll
      for (int c = 0; c < 8; c++) {
        const char* kp = smem + pb * 16384 + (jt * 16 + c16) * 512 + (((c * 4 + quad) ^ (c16 & 7)) * 16);
        bf16x8 kfrag = *(const bf16x8*)kp;
        sacc[jt] = __builtin_amdgcn_mfma_f32_16x16x32_bf16(kfrag, qf[c], sacc[jt], 0, 0, 0);
      }
    // decay + causal: d = base - off, base per-thread/tile, off per (jt,r) hoisted
    const int base = (q0 + w * 16 + c16) - kt * 32;
    const float tb = exp2f(log2g * (float)base);
    unsigned int pk[2][2];
#pragma unroll
    for (int jt = 0; jt < 2; jt++)
#pragma unroll
      for (int s = 0; s < 2; s++) {
        int off0 = jt * 16 + quad * 4 + 2 * s;
        float v0 = (base >= off0)     ? sacc[jt][2 * s]     * tb * cinv[jt][2 * s]     : 0.0f;
        float v1 = (base >= off0 + 1) ? sacc[jt][2 * s + 1] * tb * cinv[jt][2 * s + 1] : 0.0f;
        pk[jt][s] = (unsigned int)f2bf_raw(v0) | ((unsigned int)f2bf_raw(v1) << 16);
      }
    // redistribute: target (quad Q, reg t) <- src lane (2*(Q&1)+(t>>1))*16 + c16, jt = Q>>1
    u32x4 pu;
#pragma unroll
    for (int t = 0; t < 4; t++) {
      int src = ((2 * (quad & 1) + (t >> 1)) << 4) | c16;
      unsigned int a0 = (unsigned int)__shfl((int)pk[0][t & 1], src, 64);
      unsigned int a1 = (unsigned int)__shfl((int)pk[1][t & 1], src, 64);
      pu[t] = (quad < 2) ? a0 : a1;
    }
    return __builtin_bit_cast(bf16x8, pu);
  };

  auto PV_phase = [&](bf16x8 pa) {
    const char* v_lds = smem + 32768;
#pragma unroll
    for (int n = 0; n < 32; n++) {
      bf16x8 bv = *(const bf16x8*)(v_lds + quad * 8192 + (n * 16 + c16) * 16);
      acc[n] = __builtin_amdgcn_mfma_f32_16x16x32_bf16(pa, bv, acc[n], 0, 0, 0);
    }
  };

  // ---- peel ----
  stageK(kt0);                                        // [qf(8), K0(4)]
  stageV(kt0);                                        // +V0(8)
  asm volatile("s_waitcnt vmcnt(8)" ::: "memory");    // drains qf + K0; V0 flies
  SBARR();
  bf16x8 paC = S_phase(kt0);
  if (kt0 + 1 <= ktmax) stageK(kt0 + 1);              // [V(kt0)8, K1 4]

  // ---- main loop: 3 barriers/tile ----
  for (int kt = kt0 + 1; kt <= ktmax; ++kt) {
    asm volatile("s_waitcnt vmcnt(4)" ::: "memory");  // V(kt-1) landed; K(kt) flies
    SBARR();
    PV_phase(paC);
    asm volatile("s_waitcnt lgkmcnt(0)" ::: "memory");
    SBARR();                                          // all PV V-reads drained -> V buf free
    stageV(kt);                                       // [K(kt)4, V(kt)8]
    asm volatile("s_waitcnt vmcnt(8)" ::: "memory");  // K(kt) landed; V(kt) flies
    SBARR();
    paC = S_phase(kt);
    if (kt + 1 <= ktmax) stageK(kt + 1);              // [V(kt)8, K(kt+1)4]
  }

  // ---- epilogue PV(ktmax) ----
  asm volatile("s_waitcnt vmcnt(0)" ::: "memory");
  SBARR();
  PV_phase(paC);

  // RMS: wave-local (rows w*16+quad*4+rr; dv sum over n and c16 lanes)
  float ss[4];
#pragma unroll
  for (int rr = 0; rr < 4; rr++) {
    float s = 0.f;
#pragma unroll
    for (int n = 0; n < 32; n++) { float v = acc[n][rr]; s += v * v; }
    s += __shfl_xor(s, 1);
    s += __shfl_xor(s, 2);
    s += __shfl_xor(s, 4);
    s += __shfl_xor(s, 8);
    ss[rr] = rsqrtf(s * (1.0f / DVv) + EPSf);
  }

  __syncthreads();  // all K/V LDS reads done before o_lds alias writes
#pragma unroll
  for (int n = 0; n < 32; n++) {
    int col = n * 16 + c16;
    float gw = gnw[col];
#pragma unroll
    for (int rr = 0; rr < 4; rr++) {
      int row = w * 16 + quad * 4 + rr;
      o_lds[row * 512 + col] = __float2bfloat16(acc[n][rr] * ss[rr] * gw);
    }
  }
  __syncthreads();

#pragma unroll
  for (int it = 0; it < 16; it++) {
    int cid = it * 256 + tid;
    int row = cid >> 6;
    int cp = (cid & 63) * 8;
    const ushort_t* gp = (const ushort_t*)g + ((size_t)(b * Tn + q0 + row) * NH + h) * DVv + cp;
    us8 gv = *(const us8*)gp;
    us8 ov;
#pragma unroll
    for (int e = 0; e < 8; e++) {
      float gf = bf2f_raw(gv[e]);
      float gate = gf / (1.0f + expf(-gf));
      float of = __bfloat162float(o_lds[row * 512 + cp + e]);
      ov[e] = f2bf_raw(of * gate);
    }
    *(us8*)((ushort_t*)X + ((size_t)(b * Tn + q0 + row) * NH + h) * DVv + cp) = ov;
  }
}

extern "C" void kernel_launch(void* const* d_in, const int* in_sizes, int n_in,
                              void* d_out, int out_size, void* d_ws, size_t ws_size,
                              hipStream_t stream) {
  const float* hs  = (const float*)d_in[0];
  const float* Wq  = (const float*)d_in[1];
  const float* Wk  = (const float*)d_in[2];
  const float* Wv  = (const float*)d_in[3];
  const float* Wg  = (const float*)d_in[4];
  const float* Wo  = (const float*)d_in[5];
  const float* gnw = (const float*)d_in[6];
  float* out = (float*)d_out;
  char* ws = (char*)d_ws;

  bf16* hsb = (bf16*)(ws);                    // 16 MB
  bf16* WqT = (bf16*)(ws + 16777216);         //  8 MB  } contiguous [4096][2048] for fused qk
  bf16* WkT = (bf16*)(ws + 25165824);         //  8 MB  }
  bf16* WvT = (bf16*)(ws + 33554432);         // 16 MB  } contiguous [8192][2048] for fused vg
  bf16* WgT = (bf16*)(ws + 50331648);         // 16 MB  }
  char* vSb = ws;                              // alias hsb/WqT/WkT (dead after q/k/v/g GEMMs)
  bf16* WoT = (bf16*)(ws + 33554432);         // alias WvT (dead after vg GEMM)
  bf16* qb = (bf16*)(ws + 67108864);          // 16 MB
  bf16* kb = (bf16*)(ws + 83886080);          // 16 MB
  bf16* vb = (bf16*)(ws + 100663296);         // 32 MB
  bf16* gb = (bf16*)(ws + 134217728);         // 32 MB
  bf16* Xb = vb;                               // alias v (dead after vS build)

  static bool attr_done = false;
  if (!attr_done) {
    hipFuncSetAttribute((const void*)k_gemm8, hipFuncAttributeMaxDynamicSharedMemorySize, 131072);
    hipFuncSetAttribute((const void*)k_retention, hipFuncAttributeMaxDynamicSharedMemorySize, 65536);
    attr_done = true;
  }

  dim3 tb(32, 8);

  k_f32_to_bf16<<<8192, 256, 0, stream>>>((const float4*)hs, (ushort4*)hsb, 2097152);
  k_transpose_w<<<dim3(HID / 32, HID / 32), tb, 0, stream>>>(Wq, WqT, HID, HID);
  k_transpose_w<<<dim3(HID / 32, HID / 32), tb, 0, stream>>>(Wk, WkT, HID, HID);
  k_transpose_w<<<dim3(NH * DVv / 32, HID / 32), tb, 0, stream>>>(Wv, WvT, HID, NH * DVv);
  k_transpose_w<<<dim3(NH * DVv / 32, HID / 32), tb, 0, stream>>>(Wg, WgT, HID, NH * DVv);
  // fused q|k: C[4096][4096] = hsb @ [WqT|WkT]^T, split at n=2048 -> qb, kb
  k_gemm8<<<dim3(16, 16), 512, 131072, stream>>>(hsb, WqT, qb, kb, 2048, 4096, 4096, 2048);
  // fused v|g: C[4096][8192] = hsb @ [WvT|WgT]^T, split at n=4096 -> vb, gb
  k_gemm8<<<dim3(32, 16), 512, 131072, stream>>>(hsb, WvT, vb, gb, 4096, 4096, 8192, 2048);
  k_rope<<<16384, 256, 0, stream>>>(qb, 0.0625f);
  k_rope<<<16384, 256, 0, stream>>>(kb, 1.0f);
  k_build_vS<<<dim3(64, 16), 256, 0, stream>>>((const ushort_t*)vb, (ushort_t*)vSb);
  k_transpose_w<<<dim3(HID / 32, NH * DVv / 32), tb, 0, stream>>>(Wo, WoT, NH * DVv, HID);
  k_retention<<<512, 256, 65536, stream>>>(qb, kb, vSb, gb, gnw, Xb);
  k_gemm<false><<<dim3(16, 32), 256, 0, stream>>>(Xb, WoT, out, 4096, 2048, 4096);
}

// Round 7
// 600.513 us; speedup vs baseline: 1.0868x; 1.0868x over previous
//
#include <hip/hip_runtime.h>
#include <hip/hip_bf16.h>
#include <math.h>

#define NH 8
#define DKk 256
#define DVv 512
#define Bn 2
#define Tn 2048
#define HID 2048
#define EPSf 1e-5f

typedef __bf16 bf16x8 __attribute__((ext_vector_type(8)));
typedef float f32x4 __attribute__((ext_vector_type(4)));
typedef unsigned short us8 __attribute__((ext_vector_type(8)));
using bf16 = __hip_bfloat16;
typedef unsigned short ushort_t;

__device__ __forceinline__ void gload_lds16(const void* g, void* lds_base) {
  __builtin_amdgcn_global_load_lds(
      (const __attribute__((address_space(1))) void*)g,
      (__attribute__((address_space(3))) void*)lds_base, 16, 0, 0);
}

__device__ __forceinline__ ushort_t f2bf_raw(float f) {
  bf16 h = __float2bfloat16(f);
  return *reinterpret_cast<ushort_t*>(&h);
}
__device__ __forceinline__ float bf2f_raw(ushort_t u) {
  union { unsigned int i; float f; } v; v.i = ((unsigned int)u) << 16; return v.f;
}

// ---------------- fp32 -> bf16 elementwise (vectorized x4) ----------------
__global__ void k_f32_to_bf16(const float4* __restrict__ in, ushort4* __restrict__ out, int n4) {
  int i = blockIdx.x * blockDim.x + threadIdx.x;
  if (i >= n4) return;
  float4 v = in[i];
  ushort4 o;
  o.x = f2bf_raw(v.x); o.y = f2bf_raw(v.y); o.z = f2bf_raw(v.z); o.w = f2bf_raw(v.w);
  out[i] = o;
}

// ---------------- fp32 a + b -> out (vectorized x4), split-K reduce ----------------
__global__ void k_add2_f32(const float4* __restrict__ a, const float4* __restrict__ b,
                           float4* __restrict__ o, int n4) {
  int i = blockIdx.x * blockDim.x + threadIdx.x;
  if (i >= n4) return;
  float4 x = a[i], y = b[i];
  float4 r; r.x = x.x + y.x; r.y = x.y + y.y; r.z = x.z + y.z; r.w = x.w + y.w;
  o[i] = r;
}

// ---------------- W (K,N) fp32 -> WT (N,K) bf16 ----------------
__global__ void k_transpose_w(const float* __restrict__ W, bf16* __restrict__ WT, int K, int N) {
  __shared__ float t[32][33];
  int n0 = blockIdx.x * 32, k0 = blockIdx.y * 32;
  int tx = threadIdx.x, ty = threadIdx.y;
#pragma unroll
  for (int i = 0; i < 4; i++)
    t[ty + i * 8][tx] = W[(size_t)(k0 + ty + i * 8) * N + n0 + tx];
  __syncthreads();
#pragma unroll
  for (int i = 0; i < 4; i++)
    WT[(size_t)(n0 + ty + i * 8) * K + k0 + tx] = __float2bfloat16(t[tx][ty + i * 8]);
}

// ---------------- v (b,t,h,dv) bf16 -> vS[bh][kt][chunk(4)][dv(512)] 16B units ----------------
__global__ void k_build_vS(const ushort_t* __restrict__ v, ushort_t* __restrict__ vS) {
  __shared__ ushort_t t[32 * 520];
  const int tid = threadIdx.x;
  const int kt = blockIdx.x;
  const int bh = blockIdx.y;
  const int b = bh >> 3, h = bh & 7;
#pragma unroll
  for (int r = 0; r < 8; r++) {
    int j = r * 4 + (tid >> 6);
    int vec = tid & 63;
    us8 d = *(const us8*)(v + (((size_t)(b * Tn + kt * 32 + j) * NH + h) * DVv) + vec * 8);
    *(us8*)(&t[j * 520 + vec * 8]) = d;
  }
  __syncthreads();
#pragma unroll
  for (int u = 0; u < 8; u++) {
    int uid = u * 256 + tid;
    int chunk = uid >> 9;
    int dv = uid & 511;
    us8 o;
#pragma unroll
    for (int jj = 0; jj < 8; jj++) o[jj] = t[(chunk * 8 + jj) * 520 + dv];
    *(us8*)(vS + ((size_t)(bh * 64 + kt) * 2048 + chunk * 512 + dv) * 8) = o;
  }
}

// ---------------- RoPE in-place on bf16 (b,t,h,dk), scale folded ----------------
__global__ void k_rope(bf16* __restrict__ x, float scale) {
  int tid = blockIdx.x * 256 + threadIdx.x;
  int i = tid & 127;
  int h = (tid >> 7) & 7;
  int t = (tid >> 10) & (Tn - 1);
  int b = tid >> 21;
  float inv = exp2f(-(float)i * (13.287712379549449f / 128.0f));
  float ang = (float)t * inv;
  float s, c;
  sincosf(ang, &s, &c);
  size_t base = ((size_t)(b * Tn + t) * NH + h) * DKk + i;
  float x1 = __bfloat162float(x[base]);
  float x2 = __bfloat162float(x[base + 128]);
  x[base]       = __float2bfloat16((x1 * c - x2 * s) * scale);
  x[base + 128] = __float2bfloat16((x2 * c + x1 * s) * scale);
}

// ================= 256x256 8-phase GEMM, v3 (R5-measured best: 45% MfmaUtil) =================
// Per phase: {ds-read subtile ∥ stage 1 half-tile ∥ 16 MFMA}; quadrant order Q00,Q10,Q01,Q11;
// reads 12,8,4,0 per 4 phases; stages B(t+1)@ph1/2, A(t+2)@ph3/4, B(t+2)@ph5/6, A(t+3)@ph7/8;
// vmcnt(4) at ph4/ph8 only. Full region ledger verified in R5. DO NOT add counted-lgkm
// read-ahead: measured regression in R6 (45.3 -> 39.4 MfmaUtil, FETCH +6.6MB).
// Split-K: blockIdx.z selects K-half (Kloop elems, row stride Kstride); F32S=true writes
// fp32 partial (O0 for z=0, O1 for z=1) for a following k_add2_f32 reduce.
#define BARX() asm volatile("s_barrier" ::: "memory")
#define LGKM0() { asm volatile("s_waitcnt lgkmcnt(0)" ::: "memory"); __builtin_amdgcn_sched_barrier(0); }
#define VMW4() asm volatile("s_waitcnt vmcnt(4)" ::: "memory")
#define VMW0() asm volatile("s_waitcnt vmcnt(0)" ::: "memory")
#define PRIO1 __builtin_amdgcn_s_setprio(1)
#define PRIO0 __builtin_amdgcn_s_setprio(0)

#define QUADQ(MB, NB)                                                              \
  { _Pragma("unroll") for (int kk_ = 0; kk_ < 2; ++kk_)                            \
    _Pragma("unroll") for (int mf_ = 0; mf_ < 4; ++mf_)                            \
    _Pragma("unroll") for (int nf_ = 0; nf_ < 2; ++nf_)                            \
      acc[(MB) + mf_][(NB) + nf_] = __builtin_amdgcn_mfma_f32_16x16x32_bf16(       \
          ar[(MB) + mf_][kk_], br[(NB) + nf_][kk_],                                \
          acc[(MB) + mf_][(NB) + nf_], 0, 0, 0); }

template <bool F32S>
__global__ __launch_bounds__(512, 2) void k_gemm8(const bf16* __restrict__ A, const bf16* __restrict__ BT,
                                                  void* __restrict__ O0, void* __restrict__ O1,
                                                  int nsplit, int M, int Ntot, int Kloop, int Kstride) {
  extern __shared__ char lds[];
  const int tid = threadIdx.x;
  const int lane = tid & 63;
  const int w = tid >> 6;        // 0..7
  const int wr = w >> 2;         // 0..1 (M half)
  const int wc = w & 3;          // 0..3 (N quarter)
  const int quad = lane >> 4, c16 = lane & 15;
  const int m0 = blockIdx.y * 256, n0 = blockIdx.x * 256;
  const int ks = blockIdx.z;

  const bf16* Ab = A + (size_t)ks * Kloop;
  const bf16* Bb = BT + (size_t)ks * Kloop;

  const int srow = (w << 4) | (lane >> 3);
  const int gsw = (((lane & 7) ^ (lane >> 3)) << 4);   // inverse-swizzled source granule
  const size_t rowBytes = (size_t)Kstride * 2;
  const char* aS = (const char*)(Ab + (size_t)(m0 + srow) * Kstride) + gsw;
  const char* bS = (const char*)(Bb + (size_t)(n0 + srow) * Kstride) + gsw;

  auto stage = [&](int matB, int buf, int h, int t) {
    const char* base = (matB ? bS : aS) + (size_t)h * 128 * rowBytes + (size_t)t * 128;
    char* ldst = lds + buf * 65536 + matB * 32768 + h * 16384 + w * 2048;
    gload_lds16(base, ldst);
    gload_lds16(base + 8 * rowBytes, ldst + 1024);
  };
  auto ldA = [&](int buf, int mf, int kk) -> bf16x8 {
    int row = wr * 128 + mf * 16 + c16;
    return *(const bf16x8*)(lds + buf * 65536 + row * 128 + ((((kk << 2) | quad) ^ (c16 & 7)) << 4));
  };
  auto ldB = [&](int buf, int nf, int kk) -> bf16x8 {
    int row = wc * 64 + nf * 16 + c16;
    return *(const bf16x8*)(lds + buf * 65536 + 32768 + row * 128 + ((((kk << 2) | quad) ^ (c16 & 7)) << 4));
  };

  f32x4 acc[8][4];
  const f32x4 fz = {0.f, 0.f, 0.f, 0.f};
#pragma unroll
  for (int i = 0; i < 8; i++)
#pragma unroll
    for (int j = 0; j < 4; j++) acc[i][j] = fz;
  bf16x8 ar[8][2], br[4][2];

  const int nT = Kloop >> 6;
  const int nIter = nT >> 1;

  // prologue: tile0 full + tile1 A -> 12 loads; vmcnt(4) leaves t1.A in flight
  stage(0, 0, 0, 0); stage(0, 0, 1, 0);
  stage(1, 0, 0, 0); stage(1, 0, 1, 0);
  stage(0, 1, 0, 1); stage(0, 1, 1, 1);
  VMW4();
  BARX();

  for (int it = 0; it < nIter; ++it) {
    const int t = it * 2;
    const bool last = (it == nIter - 1);
    // ---- ph1: ds A0-3 + B01 (buf0); stage (t+1)B0; Q00 ----
#pragma unroll
    for (int mf = 0; mf < 4; ++mf) { ar[mf][0] = ldA(0, mf, 0); ar[mf][1] = ldA(0, mf, 1); }
#pragma unroll
    for (int nf = 0; nf < 2; ++nf) { br[nf][0] = ldB(0, nf, 0); br[nf][1] = ldB(0, nf, 1); }
    stage(1, 1, 0, t + 1);
    BARX(); LGKM0();
    PRIO1; QUADQ(0, 0); PRIO0;
    BARX();
    // ---- ph2: ds A4-7 (buf0); stage (t+1)B1; Q10 ----
#pragma unroll
    for (int mf = 4; mf < 8; ++mf) { ar[mf][0] = ldA(0, mf, 0); ar[mf][1] = ldA(0, mf, 1); }
    stage(1, 1, 1, t + 1);
    BARX(); LGKM0();
    PRIO1; QUADQ(4, 0); PRIO0;
    BARX();
    // ---- ph3: ds B23 (buf0); stage (t+2)A0; Q01 ----
#pragma unroll
    for (int nf = 2; nf < 4; ++nf) { br[nf][0] = ldB(0, nf, 0); br[nf][1] = ldB(0, nf, 1); }
    if (!last) stage(0, 0, 0, t + 2);
    BARX(); LGKM0();
    PRIO1; QUADQ(0, 2); PRIO0;
    BARX();
    // ---- ph4: stage (t+2)A1; Q11; vmcnt(4) -> tile t+1 landed ----
    if (!last) stage(0, 0, 1, t + 2);
    BARX();
    PRIO1; QUADQ(4, 2); PRIO0;
    if (!last) { VMW4(); } else { VMW0(); }
    BARX();
    // ---- ph5: ds A0-3 + B01 (buf1); stage (t+2)B0; Q00 ----
#pragma unroll
    for (int mf = 0; mf < 4; ++mf) { ar[mf][0] = ldA(1, mf, 0); ar[mf][1] = ldA(1, mf, 1); }
#pragma unroll
    for (int nf = 0; nf < 2; ++nf) { br[nf][0] = ldB(1, nf, 0); br[nf][1] = ldB(1, nf, 1); }
    if (!last) stage(1, 0, 0, t + 2);
    BARX(); LGKM0();
    PRIO1; QUADQ(0, 0); PRIO0;
    BARX();
    // ---- ph6: ds A4-7 (buf1); stage (t+2)B1; Q10 ----
#pragma unroll
    for (int mf = 4; mf < 8; ++mf) { ar[mf][0] = ldA(1, mf, 0); ar[mf][1] = ldA(1, mf, 1); }
    if (!last) stage(1, 0, 1, t + 2);
    BARX(); LGKM0();
    PRIO1; QUADQ(4, 0); PRIO0;
    BARX();
    // ---- ph7: ds B23 (buf1); stage (t+3)A0; Q01 ----
#pragma unroll
    for (int nf = 2; nf < 4; ++nf) { br[nf][0] = ldB(1, nf, 0); br[nf][1] = ldB(1, nf, 1); }
    if (!last) stage(0, 1, 0, t + 3);
    BARX(); LGKM0();
    PRIO1; QUADQ(0, 2); PRIO0;
    BARX();
    // ---- ph8: stage (t+3)A1; Q11; vmcnt(4) ----
    if (!last) stage(0, 1, 1, t + 3);
    BARX();
    PRIO1; QUADQ(4, 2); PRIO0;
    if (!last) VMW4();
    BARX();
  }

  if (F32S) {
    // split-K fp32 partial: z selects buffer, full N width
    float* Ob = (float*)(ks ? O1 : O0);
#pragma unroll
    for (int mf = 0; mf < 8; ++mf)
#pragma unroll
      for (int nf = 0; nf < 4; ++nf)
#pragma unroll
        for (int rr = 0; rr < 4; ++rr) {
          int m = m0 + wr * 128 + mf * 16 + quad * 4 + rr;
          int n = n0 + wc * 64 + nf * 16 + c16;
          Ob[(size_t)m * Ntot + n] = acc[mf][nf][rr];
        }
  } else {
    // dual bf16 outputs split at n = nsplit
    bf16* Ob; int ldo, nc0;
    if (n0 < nsplit) { Ob = (bf16*)O0; ldo = nsplit; nc0 = n0; }
    else             { Ob = (bf16*)O1; ldo = Ntot - nsplit; nc0 = n0 - nsplit; }
#pragma unroll
    for (int mf = 0; mf < 8; ++mf)
#pragma unroll
      for (int nf = 0; nf < 4; ++nf)
#pragma unroll
        for (int rr = 0; rr < 4; ++rr) {
          int m = m0 + wr * 128 + mf * 16 + quad * 4 + rr;
          int n = nc0 + wc * 64 + nf * 16 + c16;
          Ob[(size_t)m * ldo + n] = __float2bfloat16(acc[mf][nf][rr]);
        }
  }
}

// ---------------- Retention v4 (R5-measured best): rotated loop {PV(t-1); S(t)} ----------------
// K-dbuf + V-sbuf + P-dbuf, LDS 76.8KB -> 2 blocks/CU + counted-vmcnt pipelining.
// Ledger verified in R4/R5. (v5 swapped-S + shfl redistribute regressed in R6 — do not reapply.)
__global__ __launch_bounds__(256, 2) void k_retention(const bf16* __restrict__ q, const bf16* __restrict__ k,
                                                      const char* __restrict__ vS, const bf16* __restrict__ g,
                                                      const float* __restrict__ gnw, bf16* __restrict__ X) {
  extern __shared__ char smem[];
  ushort_t* p_lds_base = (ushort_t*)(smem + 65536);
  float* red = (float*)(smem + 75776);
  bf16* o_lds = (bf16*)smem;   // epilogue alias (64KB)

  const int tid = threadIdx.x;
  const int l = tid & 63, w = tid >> 6;
  const int quad = l >> 4, c16 = l & 15;

  const int bid = blockIdx.x;
  const int u = (bid & 255) >> 4;
  const int qt = (bid < 256) ? (31 - u) : u;   // heavy half then light half
  const int bh = bid & 15;
  const int b = bh >> 3, h = bh & 7;
  const int q0 = qt * 64;

  bf16x8 qf[8];
  {
    const bf16* qrow = q + ((size_t)(b * Tn + q0 + w * 16 + c16) * NH + h) * DKk + quad * 8;
#pragma unroll
    for (int c = 0; c < 8; c++) qf[c] = *(const bf16x8*)(qrow + c * 32);
  }

  const float log2g = log2f(1.0f - exp2f(-5.0f - (float)h));

  f32x4 acc[4][8];
  const f32x4 fz = {0.f, 0.f, 0.f, 0.f};
#pragma unroll
  for (int rt = 0; rt < 4; rt++)
#pragma unroll
    for (int n = 0; n < 8; n++) acc[rt][n] = fz;

  const int ktmax = 2 * qt + 1;
  const float Dcut = 30.0f / (-log2g);
  int kt0 = (int)fmaxf(0.0f, floorf(((float)q0 - Dcut) * (1.0f / 32.0f)));

  const char* vS_tilebase = vS + (size_t)(bh * 64) * 32768;

  auto stageK = [&](int kt) {
    const int pb = (kt - kt0) & 1;
#pragma unroll
    for (int i = 0; i < 4; i++) {
      int instr = w * 4 + i;
      int j = instr * 2 + (l >> 5);
      int cg = (l & 31) ^ (j & 7);
      const char* gp = (const char*)(k + ((size_t)(b * Tn + kt * 32 + j) * NH + h) * DKk) + cg * 16;
      gload_lds16(gp, smem + pb * 16384 + instr * 1024);
    }
  };
  auto stageV = [&](int kt) {
#pragma unroll
    for (int i = 0; i < 8; i++) {
      int instr = w * 8 + i;
      const char* gp = vS_tilebase + (size_t)kt * 32768 + instr * 1024 + l * 16;
      gload_lds16(gp, smem + 32768 + instr * 1024);
    }
  };

  auto S_phase = [&](int kt) {
    const int pb = (kt - kt0) & 1;
    f32x4 sacc[2] = {fz, fz};
#pragma unroll
    for (int jt = 0; jt < 2; jt++)
#pragma unroll
      for (int c = 0; c < 8; c++) {
        const char* kp = smem + pb * 16384 + (jt * 16 + c16) * 512 + (((c * 4 + quad) ^ (c16 & 7)) * 16);
        bf16x8 bfrag = *(const bf16x8*)kp;
        sacc[jt] = __builtin_amdgcn_mfma_f32_16x16x32_bf16(qf[c], bfrag, sacc[jt], 0, 0, 0);
      }
    ushort_t* pbuf = p_lds_base + pb * 2560;
#pragma unroll
    for (int jt = 0; jt < 2; jt++)
#pragma unroll
      for (int r = 0; r < 4; r++) {
        int ig = q0 + w * 16 + quad * 4 + r;
        int jg = kt * 32 + jt * 16 + c16;
        int d = ig - jg;
        float val = (d >= 0) ? sacc[jt][r] * exp2f(log2g * (float)d) : 0.0f;
        pbuf[(w * 16 + quad * 4 + r) * 40 + jt * 16 + c16] = f2bf_raw(val);
      }
  };

  auto PV_phase = [&](int kt) {
    const int pb = (kt - kt0) & 1;
    const char* pbuf = (const char*)(p_lds_base + pb * 2560);
    bf16x8 pa[4];
#pragma unroll
    for (int rt = 0; rt < 4; rt++)
      pa[rt] = *(const bf16x8*)(pbuf + (rt * 16 + c16) * 80 + quad * 16);
    const char* v_lds = smem + 32768;
#pragma unroll
    for (int n = 0; n < 8; n++) {
      bf16x8 bv = *(const bf16x8*)(v_lds + quad * 8192 + (w * 128 + n * 16 + c16) * 16);
#pragma unroll
      for (int rt = 0; rt < 4; rt++)
        acc[rt][n] = __builtin_amdgcn_mfma_f32_16x16x32_bf16(pa[rt], bv, acc[rt][n], 0, 0, 0);
    }
  };

#define SBARR() { __builtin_amdgcn_sched_barrier(0); __builtin_amdgcn_s_barrier(); }
#define WLGKM0() { asm volatile("s_waitcnt lgkmcnt(0)" ::: "memory"); }

  // ---- peeled first iteration (S-only) ----
  stageK(kt0);                                        // out: K(kt0)(4)  [+qf(8) older]
  stageV(kt0);                                        // out: +V(kt0)(8)
  asm volatile("s_waitcnt vmcnt(8)" ::: "memory");    // drains qf + K(kt0); V(kt0) flies
  SBARR();
  S_phase(kt0);
  if (kt0 + 1 <= ktmax) stageK(kt0 + 1);              // out: V(kt0)(8), K(kt0+1)(4)
  WLGKM0(); SBARR();

  // ---- main loop ----
  for (int kt = kt0 + 1; kt <= ktmax; ++kt) {
    asm volatile("s_waitcnt vmcnt(4)" ::: "memory");  // V(kt-1) landed; K(kt) flies
    SBARR();
    PV_phase(kt - 1);
    WLGKM0(); SBARR();                                // V buf + p[kt-1] free
    stageV(kt);                                       // out: K(kt)(4), V(kt)(8)
    asm volatile("s_waitcnt vmcnt(8)" ::: "memory");  // K(kt) landed; V(kt) flies
    SBARR();
    S_phase(kt);
    if (kt + 1 <= ktmax) stageK(kt + 1);              // out: V(kt)(8), K(kt+1)(4)
    WLGKM0(); SBARR();                                // p[kt] visible
  }

  // ---- epilogue PV(ktmax) ----
  asm volatile("s_waitcnt vmcnt(0)" ::: "memory");
  SBARR();
  PV_phase(ktmax);

  // RMS: wave has 128-dv partial for all 64 rows -> cross-wave combine via red
  __syncthreads();
#pragma unroll
  for (int rt = 0; rt < 4; rt++)
#pragma unroll
    for (int r = 0; r < 4; r++) {
      float s = 0.f;
#pragma unroll
      for (int n = 0; n < 8; n++) { float v = acc[rt][n][r]; s += v * v; }
      s += __shfl_xor(s, 1);
      s += __shfl_xor(s, 2);
      s += __shfl_xor(s, 4);
      s += __shfl_xor(s, 8);
      if (c16 == 0) red[(rt * 16 + quad * 4 + r) * 4 + w] = s;
    }
  __syncthreads();
  float ss[4][4];
#pragma unroll
  for (int rt = 0; rt < 4; rt++)
#pragma unroll
    for (int r = 0; r < 4; r++) {
      int row = rt * 16 + quad * 4 + r;
      float tot = red[row * 4] + red[row * 4 + 1] + red[row * 4 + 2] + red[row * 4 + 3];
      ss[rt][r] = rsqrtf(tot * (1.0f / DVv) + EPSf);
    }
  __syncthreads();

#pragma unroll
  for (int n = 0; n < 8; n++) {
    int col = w * 128 + n * 16 + c16;
    float gw = gnw[col];
#pragma unroll
    for (int rt = 0; rt < 4; rt++)
#pragma unroll
      for (int r = 0; r < 4; r++) {
        int row = rt * 16 + quad * 4 + r;
        o_lds[row * 512 + col] = __float2bfloat16(acc[rt][n][r] * ss[rt][r] * gw);
      }
  }
  __syncthreads();

#pragma unroll
  for (int it = 0; it < 16; it++) {
    int cid = it * 256 + tid;
    int row = cid >> 6;
    int cp = (cid & 63) * 8;
    const ushort_t* gp = (const ushort_t*)g + ((size_t)(b * Tn + q0 + row) * NH + h) * DVv + cp;
    us8 gv = *(const us8*)gp;
    us8 ov;
#pragma unroll
    for (int e = 0; e < 8; e++) {
      float gf = bf2f_raw(gv[e]);
      float gate = gf / (1.0f + expf(-gf));
      float of = __bfloat162float(o_lds[row * 512 + cp + e]);
      ov[e] = f2bf_raw(of * gate);
    }
    *(us8*)((ushort_t*)X + ((size_t)(b * Tn + q0 + row) * NH + h) * DVv + cp) = ov;
  }
}

extern "C" void kernel_launch(void* const* d_in, const int* in_sizes, int n_in,
                              void* d_out, int out_size, void* d_ws, size_t ws_size,
                              hipStream_t stream) {
  const float* hs  = (const float*)d_in[0];
  const float* Wq  = (const float*)d_in[1];
  const float* Wk  = (const float*)d_in[2];
  const float* Wv  = (const float*)d_in[3];
  const float* Wg  = (const float*)d_in[4];
  const float* Wo  = (const float*)d_in[5];
  const float* gnw = (const float*)d_in[6];
  float* out = (float*)d_out;
  char* ws = (char*)d_ws;

  bf16* hsb = (bf16*)(ws);                    // 16 MB
  bf16* WqT = (bf16*)(ws + 16777216);         //  8 MB  } contiguous [4096][2048] for fused qk
  bf16* WkT = (bf16*)(ws + 25165824);         //  8 MB  }
  bf16* WvT = (bf16*)(ws + 33554432);         // 16 MB  } contiguous [8192][2048] for fused vg
  bf16* WgT = (bf16*)(ws + 50331648);         // 16 MB  }
  char* vSb = ws;                              // alias hsb/WqT/WkT (dead after q/k/v/g GEMMs)
  bf16* WoT = (bf16*)(ws + 33554432);         // alias WvT (dead after vg GEMM)
  bf16* qb = (bf16*)(ws + 67108864);          // 16 MB
  bf16* kb = (bf16*)(ws + 83886080);          // 16 MB
  bf16* vb = (bf16*)(ws + 100663296);         // 32 MB
  bf16* gb = (bf16*)(ws + 134217728);         // 32 MB
  bf16* Xb = vb;                               // alias v (dead after vS build)
  float* p0 = (float*)ws;                      // 32 MB fp32 partial (alias vSb, dead after retention)
  float* p1 = (float*)(ws + 50331648);         // 32 MB fp32 partial (alias WgT+qb, dead after retention)

  static bool attr_done = false;
  if (!attr_done) {
    hipFuncSetAttribute((const void*)k_gemm8<false>, hipFuncAttributeMaxDynamicSharedMemorySize, 131072);
    hipFuncSetAttribute((const void*)k_gemm8<true>, hipFuncAttributeMaxDynamicSharedMemorySize, 131072);
    hipFuncSetAttribute((const void*)k_retention, hipFuncAttributeMaxDynamicSharedMemorySize, 76800);
    attr_done = true;
  }

  dim3 tb(32, 8);

  k_f32_to_bf16<<<8192, 256, 0, stream>>>((const float4*)hs, (ushort4*)hsb, 2097152);
  k_transpose_w<<<dim3(HID / 32, HID / 32), tb, 0, stream>>>(Wq, WqT, HID, HID);
  k_transpose_w<<<dim3(HID / 32, HID / 32), tb, 0, stream>>>(Wk, WkT, HID, HID);
  k_transpose_w<<<dim3(NH * DVv / 32, HID / 32), tb, 0, stream>>>(Wv, WvT, HID, NH * DVv);
  k_transpose_w<<<dim3(NH * DVv / 32, HID / 32), tb, 0, stream>>>(Wg, WgT, HID, NH * DVv);
  // fused q|k: C[4096][4096] = hsb @ [WqT|WkT]^T, split at n=2048 -> qb, kb
  k_gemm8<false><<<dim3(16, 16), 512, 131072, stream>>>(hsb, WqT, qb, kb, 2048, 4096, 4096, 2048, 2048);
  // fused v|g: C[4096][8192] = hsb @ [WvT|WgT]^T, split at n=4096 -> vb, gb
  k_gemm8<false><<<dim3(32, 16), 512, 131072, stream>>>(hsb, WvT, vb, gb, 4096, 4096, 8192, 2048, 2048);
  k_rope<<<16384, 256, 0, stream>>>(qb, 0.0625f);
  k_rope<<<16384, 256, 0, stream>>>(kb, 1.0f);
  k_build_vS<<<dim3(64, 16), 256, 0, stream>>>((const ushort_t*)vb, (ushort_t*)vSb);
  k_transpose_w<<<dim3(HID / 32, NH * DVv / 32), tb, 0, stream>>>(Wo, WoT, NH * DVv, HID);
  k_retention<<<512, 256, 76800, stream>>>(qb, kb, vSb, gb, gnw, Xb);
  // out-proj split-K=2 through the 8-phase kernel: 256 blocks (full GPU), fp32 partials + reduce
  k_gemm8<true><<<dim3(8, 16, 2), 512, 131072, stream>>>(Xb, WoT, p0, p1, 2048, 4096, 2048, 2048, 4096);
  k_add2_f32<<<8192, 256, 0, stream>>>((const float4*)p0, (const float4*)p1, (float4*)out, 2097152);
}